// Round 2
// baseline (32.396 us; speedup 1.0000x reference)
//
#include <hip/hip_runtime.h>
#include <hip/hip_cooperative_groups.h>

namespace cg = cooperative_groups;

// TripletLoss: N=16384 rows, M=4096 cols.
// loss_r = max( (s1>=s2 ? d1-d2 : d2-d1) + 100, 0 ),  out = sum_r loss_r / N
// Latency-bound random gather. Single cooperative launch: 64 blocks x 256
// threads (one thread per row), deterministic two-stage reduce + grid.sync,
// block 0 does the fixed-order final sum. One graph node total.

#define N_ROWS 16384
#define M_COLS 4096
#define MARGIN 100.0f
#define NBLOCKS 64
#define NTHREADS 256

__global__ __launch_bounds__(NTHREADS) void triplet_all(
    const float* __restrict__ D,
    const float* __restrict__ S,
    const int*   __restrict__ P,
    float* __restrict__ out,
    float* __restrict__ partial)
{
    const int r = blockIdx.x * NTHREADS + threadIdx.x;   // exactly N_ROWS threads

    // permutations is (N,3) int32; need columns 1 and 2 (adjacent)
    const int i1 = P[3 * r + 1];
    const int i2 = P[3 * r + 2];

    const float* Drow = D + (size_t)r * M_COLS;
    const float* Srow = S + (size_t)r * M_COLS;

    const float d1 = Drow[i1];
    const float d2 = Drow[i2];
    const float s1 = Srow[i1];
    const float s2 = Srow[i2];

    const float diff = (s1 >= s2) ? (d1 - d2) : (d2 - d1);
    float loss = fmaxf(diff + MARGIN, 0.0f);

    // wave (64-lane) reduction
    #pragma unroll
    for (int off = 32; off > 0; off >>= 1)
        loss += __shfl_down(loss, off);

    __shared__ float wsum[NTHREADS / 64];
    const int lane = threadIdx.x & 63;
    const int wid  = threadIdx.x >> 6;
    if (lane == 0) wsum[wid] = loss;
    __syncthreads();

    if (threadIdx.x == 0) {
        float s = 0.0f;
        #pragma unroll
        for (int w = 0; w < NTHREADS / 64; ++w) s += wsum[w];
        partial[blockIdx.x] = s;
        __threadfence();   // device-scope visibility across XCDs before grid sync
    }

    cg::this_grid().sync();

    // block 0, first wave: fixed-order final reduction (deterministic)
    if (blockIdx.x == 0 && threadIdx.x < NBLOCKS) {
        float v = partial[threadIdx.x];
        #pragma unroll
        for (int off = 32; off > 0; off >>= 1)
            v += __shfl_down(v, off);
        if (threadIdx.x == 0)
            out[0] = v * (1.0f / (float)N_ROWS);
    }
}

extern "C" void kernel_launch(void* const* d_in, const int* in_sizes, int n_in,
                              void* d_out, int out_size, void* d_ws, size_t ws_size,
                              hipStream_t stream)
{
    const float* D = (const float*)d_in[0];   // distances   (N, M) f32
    const float* S = (const float*)d_in[1];   // similarities(N, M) f32
    const int*   P = (const int*)  d_in[2];   // permutations(N, 3) int32
    float* out     = (float*)d_out;
    float* partial = (float*)d_ws;            // NBLOCKS floats of scratch

    void* args[] = { (void*)&D, (void*)&S, (void*)&P, (void*)&out, (void*)&partial };
    hipLaunchCooperativeKernel((void*)triplet_all, dim3(NBLOCKS), dim3(NTHREADS),
                               args, 0, stream);
}

// Round 3
// 9.577 us; speedup vs baseline: 3.3827x; 3.3827x over previous
//
#include <hip/hip_runtime.h>

// TripletLoss: N=16384 rows, M=4096 cols.
// loss_r = max( (s1>=s2 ? d1-d2 : d2-d1) + 100, 0 ),  out = sum_r loss_r / N
//
// Single kernel node. 64 worker blocks (one thread per row) publish partials
// as (float_bits<<32)|MAGIC via device-scope release stores; finalizer block
// spins with device-scope acquire loads, then reduces in fixed order.
// Deterministic: partials are pure functions of inputs; final sum order fixed.

#define N_ROWS   16384
#define M_COLS   4096
#define MARGIN   100.0f
#define NWORK    64
#define NTHREADS 256
#define MAGIC    0x5A17C0DEu

__global__ __launch_bounds__(NTHREADS) void triplet_one(
    const float* __restrict__ D,
    const float* __restrict__ S,
    const int*   __restrict__ P,
    float* __restrict__ out,
    unsigned long long* __restrict__ slots)
{
    if (blockIdx.x < NWORK) {
        const int r = blockIdx.x * NTHREADS + threadIdx.x;   // one thread per row

        // permutations (N,3) int32; need cols 1 and 2
        const int i1 = P[3 * r + 1];
        const int i2 = P[3 * r + 2];

        const float* Drow = D + (size_t)r * M_COLS;
        const float* Srow = S + (size_t)r * M_COLS;

        const float d1 = Drow[i1];
        const float d2 = Drow[i2];
        const float s1 = Srow[i1];
        const float s2 = Srow[i2];

        const float diff = (s1 >= s2) ? (d1 - d2) : (d2 - d1);
        float loss = fmaxf(diff + MARGIN, 0.0f);

        // 64-lane wave reduction
        #pragma unroll
        for (int off = 32; off > 0; off >>= 1)
            loss += __shfl_down(loss, off);

        __shared__ float wsum[NTHREADS / 64];
        const int lane = threadIdx.x & 63;
        const int wid  = threadIdx.x >> 6;
        if (lane == 0) wsum[wid] = loss;
        __syncthreads();

        if (threadIdx.x == 0) {
            float s = 0.0f;
            #pragma unroll
            for (int w = 0; w < NTHREADS / 64; ++w) s += wsum[w];
            const unsigned long long pk =
                ((unsigned long long)__float_as_uint(s) << 32) | (unsigned long long)MAGIC;
            __hip_atomic_store(&slots[blockIdx.x], pk,
                               __ATOMIC_RELEASE, __HIP_MEMORY_SCOPE_AGENT);
        }
    } else {
        // finalizer block: first wave spins on the 64 slots
        if (threadIdx.x < NWORK) {
            unsigned long long v;
            do {
                v = __hip_atomic_load(&slots[threadIdx.x],
                                      __ATOMIC_ACQUIRE, __HIP_MEMORY_SCOPE_AGENT);
                if ((unsigned)(v & 0xFFFFFFFFull) == MAGIC) break;
                __builtin_amdgcn_s_sleep(1);
            } while (true);

            float p = __uint_as_float((unsigned)(v >> 32));
            #pragma unroll
            for (int off = 32; off > 0; off >>= 1)
                p += __shfl_down(p, off);
            if (threadIdx.x == 0)
                out[0] = p * (1.0f / (float)N_ROWS);
        }
    }
}

extern "C" void kernel_launch(void* const* d_in, const int* in_sizes, int n_in,
                              void* d_out, int out_size, void* d_ws, size_t ws_size,
                              hipStream_t stream)
{
    const float* D = (const float*)d_in[0];   // distances   (N, M) f32
    const float* S = (const float*)d_in[1];   // similarities(N, M) f32
    const int*   P = (const int*)  d_in[2];   // permutations(N, 3) int32
    float* out     = (float*)d_out;
    unsigned long long* slots = (unsigned long long*)d_ws;  // 64 x u64 scratch

    triplet_one<<<NWORK + 1, NTHREADS, 0, stream>>>(D, S, P, out, slots);
}